// Round 7
// baseline (681.136 us; speedup 1.0000x reference)
//
#include <hip/hip_runtime.h>
#include <math.h>

#define BB 8
#define LL 2500
#define VV 50000
#define EE 100
#define FF 50
#define CC 8921
#define KK 10
#define PADW 5
#define LOUT 2501        // L + 2*PAD - K + 1
#define NLT 157          // ceil(LOUT/16)
#define LPAD (NLT * 16)  // 2512
#define NCT 140          // ceil(CC/64)
#define NT16 (NCT * 4)   // 560 16-c tiles
#define NLH 4            // l-chunks for k_attnB
#define CHLT 40          // lt per chunk (last: 37)

typedef __attribute__((ext_vector_type(8))) short bf16x8;
typedef __attribute__((ext_vector_type(4))) float f32x4;

__device__ __forceinline__ short to_bf16(float f) {
  unsigned u = __builtin_bit_cast(unsigned, f);
  u += 0x7FFFu + ((u >> 16) & 1u);  // RNE
  return (short)(u >> 16);
}

// ---------------------------------------------------------------------------
// K1: embedding + conv1d + bias + tanh -> Zp directly in MFMA frag layout
// [b][lt][kh][lane][8] bf16 (k 50..63 zero, l >= LOUT zero), via LDS
// transpose.  grid (40, B), block 256.
// ---------------------------------------------------------------------------
__global__ void k1_conv(const int* __restrict__ text,
                        const float* __restrict__ embed,
                        const float* __restrict__ convw,
                        const float* __restrict__ convb,
                        short* __restrict__ Zp) {
  __shared__ float xw[73 * 101];
  __shared__ short zt[64][72];
  const int b   = blockIdx.y;
  const int l0  = blockIdx.x * 64;
  const int tid = threadIdx.x;

  for (int i = tid; i < 64 * 72 / 2; i += 256) ((int*)zt)[i] = 0;

  for (int idx = tid; idx < 73 * 100; idx += 256) {
    int r = idx / 100;
    int e = idx - r * 100;
    int t = l0 - PADW + r;
    float v = 0.f;
    if (t >= 0 && t < LL) {
      int tok = text[b * LL + t];
      v = embed[tok * EE + e];
    }
    xw[r * 101 + e] = v;
  }
  __syncthreads();

  const int ll = tid & 63;
  const int fg = __builtin_amdgcn_readfirstlane(tid >> 6);
  const int l  = l0 + ll;

  float acc[13];
#pragma unroll
  for (int j = 0; j < 13; ++j) {
    int f = fg + 4 * j;
    acc[j] = (f < FF) ? convb[f] : 0.f;
  }

  for (int e = 0; e < EE; ++e) {
    float xk[KK];
#pragma unroll
    for (int k = 0; k < KK; ++k) xk[k] = xw[(ll + k) * 101 + e];
#pragma unroll
    for (int j = 0; j < 13; ++j) {
      int f = fg + 4 * j;
      if (f < FF) {
        const float* wp = convw + (f * EE + e) * KK;
#pragma unroll
        for (int k = 0; k < KK; ++k) acc[j] += xk[k] * wp[k];
      }
    }
  }

#pragma unroll
  for (int j = 0; j < 13; ++j) {
    int f = fg + 4 * j;
    if (f < FF) {
      float v = (l < LOUT) ? tanhf(acc[j]) : 0.f;
      zt[ll][f] = to_bf16(v);
    }
  }
  __syncthreads();

#pragma unroll
  for (int p = 0; p < 2; ++p) {
    int u    = tid + 256 * p;
    int lane = u & 63, kh = (u >> 6) & 1, i = u >> 7;
    int lt   = blockIdx.x * 4 + i;
    if (lt < NLT) {
      int lrow = i * 16 + (lane & 15);
      int k0   = 4 * (lane >> 4) + 32 * kh;
      uint2 a  = *(const uint2*)&zt[lrow][k0];
      uint2 b2 = *(const uint2*)&zt[lrow][k0 + 16];
      uint4 o; o.x = a.x; o.y = a.y; o.z = b2.x; o.w = b2.y;
      ((uint4*)Zp)[((size_t)b * NLT + lt) * 2 * 64 + kh * 64 + lane] = o;
    }
  }
}

// ---------------------------------------------------------------------------
// Pack Qw / out_w (C,F) fp32 -> frag layout bf16 [t16][kh][lane][8]
// ---------------------------------------------------------------------------
__global__ void k_packW(const float* __restrict__ W, short* __restrict__ Wp) {
  int u = blockIdx.x * 256 + threadIdx.x;
  int lane = u & 63, kh = (u >> 6) & 1, t16 = u >> 7;
  int c  = t16 * 16 + (lane & 15);
  int k0 = 4 * (lane >> 4) + 32 * kh;
  union { short s[8]; uint4 v; } o;
#pragma unroll
  for (int j = 0; j < 8; ++j) {
    int k = k0 + (j & 3) + 16 * (j >> 2);
    float val = (c < CC && k < FF) ? W[c * FF + k] : 0.f;
    o.s[j] = to_bf16(val);
  }
  ((uint4*)Wp)[u] = o.v;
}

// ---------------------------------------------------------------------------
// k_attnA: softmax denominators.  grid (NCT*BB): d[b,c] over full l range;
// writes rdinv[(b*NCT+ct)*64 + j] = 1/d.
// ---------------------------------------------------------------------------
__global__ __launch_bounds__(256) void k_attnA(
    const short* __restrict__ Zp, const short* __restrict__ Qp,
    float* __restrict__ rdinvBuf) {
  const int id   = blockIdx.x;
  const int b    = id & 7;
  const int ct   = id >> 3;
  const int tid  = threadIdx.x;
  const int w    = tid >> 6;
  const int lane = tid & 63;
  const int g    = lane >> 4, col = lane & 15;

  __shared__ float red[4][4][4][4];

  bf16x8 qf[4][2];
#pragma unroll
  for (int mf = 0; mf < 4; ++mf)
#pragma unroll
    for (int kh = 0; kh < 2; ++kh) {
      int t16 = ct * 4 + mf;
      qf[mf][kh] = ((const bf16x8*)Qp)[(t16 * 2 + kh) * 64 + lane];
    }
  const bf16x8* Zb = (const bf16x8*)Zp + (size_t)b * NLT * 2 * 64;

  float dacc[4][4];
#pragma unroll
  for (int mf = 0; mf < 4; ++mf)
#pragma unroll
    for (int r = 0; r < 4; ++r) dacc[mf][r] = 0.f;

  for (int t = 0; t < 10; ++t) {
    const int lt0 = t * 16 + w * 4;
    bf16x8 zz[4][2];
#pragma unroll
    for (int i = 0; i < 4; ++i) {
      int lt = lt0 + i; if (lt > NLT - 1) lt = NLT - 1;
      zz[i][0] = Zb[(lt * 2 + 0) * 64 + lane];
      zz[i][1] = Zb[(lt * 2 + 1) * 64 + lane];
    }
#pragma unroll
    for (int i = 0; i < 4; ++i) {
      int   l    = (lt0 + i) * 16 + col;
      float lmsk = (l < LOUT) ? 1.f : 0.f;
#pragma unroll
      for (int mf = 0; mf < 4; ++mf) {
        f32x4 acc = {0.f, 0.f, 0.f, 0.f};
        acc = __builtin_amdgcn_mfma_f32_16x16x32_bf16(qf[mf][0], zz[i][0], acc, 0, 0, 0);
        acc = __builtin_amdgcn_mfma_f32_16x16x32_bf16(qf[mf][1], zz[i][1], acc, 0, 0, 0);
#pragma unroll
        for (int r = 0; r < 4; ++r) dacc[mf][r] += lmsk * __expf(acc[r]);
      }
    }
  }

#pragma unroll
  for (int mf = 0; mf < 4; ++mf)
#pragma unroll
    for (int r = 0; r < 4; ++r) {
      float v = dacc[mf][r];
      v += __shfl_xor(v, 1); v += __shfl_xor(v, 2);
      v += __shfl_xor(v, 4); v += __shfl_xor(v, 8);
      dacc[mf][r] = v;
    }
  if (col == 0)
#pragma unroll
    for (int mf = 0; mf < 4; ++mf)
#pragma unroll
      for (int r = 0; r < 4; ++r) red[w][mf][g][r] = dacc[mf][r];
  __syncthreads();
  if (tid < 64) {
    int mf = tid >> 4, gg = (tid >> 2) & 3, r = tid & 3;
    float s = red[0][mf][gg][r] + red[1][mf][gg][r] +
              red[2][mf][gg][r] + red[3][mf][gg][r];
    rdinvBuf[(size_t)(b * NCT + ct) * 64 + tid] = 1.f / s;
  }
}

// ---------------------------------------------------------------------------
// k_attnB: recompute s, alpha = exp(s)*rdinv -> LDS tile -> 1KB nt dwordx4
// row stores; partial logits per l-chunk.  grid (NCT*BB*NLH).
// ---------------------------------------------------------------------------
__global__ __launch_bounds__(256) void k_attnB(
    const short* __restrict__ Zp, const short* __restrict__ Qp,
    const short* __restrict__ Op, const float* __restrict__ rdinvBuf,
    float* __restrict__ alpha, float* __restrict__ Lpart) {
  const int id   = blockIdx.x;
  const int b    = id & 7;
  const int rest = id >> 3;
  const int ct   = rest % NCT;
  const int lh   = rest / NCT;
  const int tid  = threadIdx.x;
  const int w    = tid >> 6;
  const int lane = tid & 63;
  const int g    = lane >> 4, col = lane & 15;
  const int cb   = ct * 64;
  const int q4   = lane >> 4, i16 = lane & 15;

  const int ltStart = lh * CHLT;
  const int ltEnd   = (ltStart + CHLT < NLT) ? ltStart + CHLT : NLT;
  const int nLt     = ltEnd - ltStart;

  __shared__ float red[4][4][4][4];
  __shared__ float rdS[64];
  __shared__ float sA[4 * 16 * 68];
  float* sAw = sA + w * (16 * 68);

  if (tid < 64) rdS[tid] = rdinvBuf[(size_t)(b * NCT + ct) * 64 + tid];

  bf16x8 qf[4][2], of[4][2];
#pragma unroll
  for (int mf = 0; mf < 4; ++mf)
#pragma unroll
    for (int kh = 0; kh < 2; ++kh) {
      int t16 = ct * 4 + mf;
      qf[mf][kh] = ((const bf16x8*)Qp)[(t16 * 2 + kh) * 64 + lane];
      of[mf][kh] = ((const bf16x8*)Op)[(t16 * 2 + kh) * 64 + lane];
    }
  const bf16x8* Zb = (const bf16x8*)Zp + (size_t)b * NLT * 2 * 64;
  __syncthreads();

  float rd[4][4];
#pragma unroll
  for (int mf = 0; mf < 4; ++mf)
#pragma unroll
    for (int r = 0; r < 4; ++r) rd[mf][r] = rdS[mf * 16 + g * 4 + r];

  float lacc[4][4];
#pragma unroll
  for (int mf = 0; mf < 4; ++mf)
#pragma unroll
    for (int r = 0; r < 4; ++r) lacc[mf][r] = 0.f;

  for (int t = 0; t < 3; ++t) {
    const int lt0r = t * 16 + w * 4;     // relative lt of this wave's 4 rows
    if (lt0r < nLt) {
      const int lt0 = ltStart + lt0r;
      bf16x8 zz[4][2];
#pragma unroll
      for (int i = 0; i < 4; ++i) {
        int lt = lt0 + i; if (lt > NLT - 1) lt = NLT - 1;
        zz[i][0] = Zb[(lt * 2 + 0) * 64 + lane];
        zz[i][1] = Zb[(lt * 2 + 1) * 64 + lane];
      }
#pragma unroll
      for (int mf = 0; mf < 4; ++mf) {
#pragma unroll
        for (int i = 0; i < 4; ++i) {
          f32x4 s = {0.f, 0.f, 0.f, 0.f}, tt = {0.f, 0.f, 0.f, 0.f};
          s  = __builtin_amdgcn_mfma_f32_16x16x32_bf16(qf[mf][0], zz[i][0], s, 0, 0, 0);
          s  = __builtin_amdgcn_mfma_f32_16x16x32_bf16(qf[mf][1], zz[i][1], s, 0, 0, 0);
          tt = __builtin_amdgcn_mfma_f32_16x16x32_bf16(of[mf][0], zz[i][0], tt, 0, 0, 0);
          tt = __builtin_amdgcn_mfma_f32_16x16x32_bf16(of[mf][1], zz[i][1], tt, 0, 0, 0);
          int l = (lt0 + i) * 16 + col;
#pragma unroll
          for (int r = 0; r < 4; ++r) {
            float a = __expf(s[r]) * rd[mf][r];
            lacc[mf][r] += (l < LOUT) ? a * tt[r] : 0.f;
            sAw[(g * 4 + r) * 68 + i * 16 + col] = a;
          }
        }
        // drain: 4 x (4 rows x 64 l) = 1KB nt dwordx4 per instruction
        const int l0w = lt0 * 16;
        if (l0w + 64 <= LOUT) {
#pragma unroll
          for (int s4 = 0; s4 < 4; ++s4) {
            int rr = s4 * 4 + q4;
            int c  = cb + mf * 16 + rr;
            if (c < CC) {
              f32x4 v = *(const f32x4*)&sAw[rr * 68 + 4 * i16];
              float* dst = alpha + (size_t)(b * CC + c) * LOUT + l0w + 4 * i16;
              __builtin_nontemporal_store(v[0], dst + 0);
              __builtin_nontemporal_store(v[1], dst + 1);
              __builtin_nontemporal_store(v[2], dst + 2);
              __builtin_nontemporal_store(v[3], dst + 3);
            }
          }
        } else {
          const int lw = l0w + lane;
#pragma unroll
          for (int rr = 0; rr < 16; ++rr) {
            int c = cb + mf * 16 + rr;
            if (lw < LOUT && c < CC)
              __builtin_nontemporal_store(
                  sAw[rr * 68 + lane],
                  &alpha[(size_t)(b * CC + c) * LOUT + lw]);
          }
        }
      }
    }
  }

  // partial logits reduction -> Lpart[lh][b*CC + c]
#pragma unroll
  for (int mf = 0; mf < 4; ++mf)
#pragma unroll
    for (int r = 0; r < 4; ++r) {
      float v = lacc[mf][r];
      v += __shfl_xor(v, 1); v += __shfl_xor(v, 2);
      v += __shfl_xor(v, 4); v += __shfl_xor(v, 8);
      lacc[mf][r] = v;
    }
  __syncthreads();
  if (col == 0)
#pragma unroll
    for (int mf = 0; mf < 4; ++mf)
#pragma unroll
      for (int r = 0; r < 4; ++r) red[w][mf][g][r] = lacc[mf][r];
  __syncthreads();
  if (tid < 64) {
    int mf = tid >> 4, gg = (tid >> 2) & 3, r = tid & 3;
    int c = cb + tid;
    if (c < CC) {
      float v = red[0][mf][gg][r] + red[1][mf][gg][r] +
                red[2][mf][gg][r] + red[3][mf][gg][r];
      Lpart[(size_t)lh * (BB * CC) + b * CC + c] = v;
    }
  }
}

// ---------------------------------------------------------------------------
// k_attnC: logits = sum_lh Lpart + outb
// ---------------------------------------------------------------------------
__global__ void k_attnC(const float* __restrict__ Lpart,
                        const float* __restrict__ outb,
                        float* __restrict__ logits) {
  int idx = blockIdx.x * 256 + threadIdx.x;
  if (idx < BB * CC) {
    int c = idx % CC;
    float v = outb[c];
#pragma unroll
    for (int lh = 0; lh < NLH; ++lh) v += Lpart[(size_t)lh * (BB * CC) + idx];
    logits[idx] = v;
  }
}

// ---------------------------------------------------------------------------
extern "C" void kernel_launch(void* const* d_in, const int* in_sizes, int n_in,
                              void* d_out, int out_size, void* d_ws, size_t ws_size,
                              hipStream_t stream) {
  const int*   text  = (const int*)d_in[0];
  const float* embed = (const float*)d_in[1];
  const float* convw = (const float*)d_in[2];
  const float* convb = (const float*)d_in[3];
  const float* Qw    = (const float*)d_in[4];
  const float* outw  = (const float*)d_in[5];
  const float* outb  = (const float*)d_in[6];

  float* out    = (float*)d_out;
  float* logits = out;
  float* alpha  = out + (size_t)BB * CC;

  short* wsS = (short*)d_ws;
  short* Zp  = wsS;                                 // B*NLT*2*64*8 shorts
  short* Qp  = Zp + (size_t)BB * NLT * 2 * 64 * 8;  // NT16*2*64*8
  short* Op  = Qp + (size_t)NT16 * 2 * 64 * 8;
  float* rdinvBuf = (float*)(Op + (size_t)NT16 * 2 * 64 * 8);  // B*NCT*64
  float* Lpart    = rdinvBuf + (size_t)BB * NCT * 64;          // NLH*B*CC

  k1_conv<<<dim3(40, BB), 256, 0, stream>>>(text, embed, convw, convb, Zp);
  k_packW<<<(NT16 * 128) / 256, 256, 0, stream>>>(Qw, Qp);
  k_packW<<<(NT16 * 128) / 256, 256, 0, stream>>>(outw, Op);
  k_attnA<<<dim3(NCT * BB), 256, 0, stream>>>(Zp, Qp, rdinvBuf);
  k_attnB<<<dim3(NCT * BB * NLH), 256, 0, stream>>>(Zp, Qp, Op, rdinvBuf,
                                                    alpha, Lpart);
  k_attnC<<<(BB * CC + 255) / 256, 256, 0, stream>>>(Lpart, outb, logits);
}